// Round 4
// baseline (596.047 us; speedup 1.0000x reference)
//
#include <hip/hip_runtime.h>
#include <hip/hip_bf16.h>

// DIAGNOSTIC ROUND — kernel launched TWICE (idempotent identical writes) to
// measure the kernel's true time-share K = dur_us(this) - 512.9 (R0 baseline).
// Kernel body is bit-identical to the R0 best (131072 blocks, one NT f4
// store/thread), which remains the fastest structure measured (512.9 us).
//
// Output: (1, 8, 4096, 4096) float32.
//   c in [0,4):  out[c,i,j] = table[seq[i]*4 + c]      (constant along j)
//   c in [4,8):  out[c,i,j] = table[seq[j]*4 + (c-4)]  (depends on j only)

#define L 4096
#define TOTAL_F4 (8u * L * L / 4u)   // 33,554,432 float4 stores

typedef float v4f __attribute__((ext_vector_type(4)));
typedef int   v4i __attribute__((ext_vector_type(4)));

__global__ __launch_bounds__(256) void SequenceEmbedding_30923764532139_kernel(
        const int* __restrict__ seq,
        const float* __restrict__ table,
        v4f* __restrict__ out) {
    unsigned idx = blockIdx.x * blockDim.x + threadIdx.x;  // float4 index, exact cover
    unsigned e = idx << 2;                                  // element index (fits: 2^27)
    unsigned c = e >> 24;                                   // channel 0..7 (wave-uniform)
    unsigned i = (e >> 12) & (L - 1);                       // row (wave-uniform)
    unsigned j = e & (L - 1);                               // col, multiple of 4

    v4f val;
    if (c < 4u) {
        float x = table[(unsigned)seq[i] * 4u + c];
        val = (v4f){x, x, x, x};
    } else {
        unsigned cc = c - 4u;
        v4i s = *(const v4i*)(seq + j);                     // coalesced, 16B aligned
        val.x = table[(unsigned)s.x * 4u + cc];
        val.y = table[(unsigned)s.y * 4u + cc];
        val.z = table[(unsigned)s.z * 4u + cc];
        val.w = table[(unsigned)s.w * 4u + cc];
    }
    __builtin_nontemporal_store(val, out + idx);
}

extern "C" void kernel_launch(void* const* d_in, const int* in_sizes, int n_in,
                              void* d_out, int out_size, void* d_ws, size_t ws_size,
                              hipStream_t stream) {
    const int*   seq   = (const int*)d_in[0];
    const float* table = (const float*)d_in[1];
    v4f*         out   = (v4f*)d_out;

    dim3 block(256);
    dim3 grid(TOTAL_F4 / 256u);  // 131,072 blocks, exact cover

    // Launch #1 — the real work.
    SequenceEmbedding_30923764532139_kernel<<<grid, block, 0, stream>>>(seq, table, out);
    // Launch #2 — identical idempotent rewrite, purely to expose the kernel's
    // time-share in dur_us (K = dur_us - 512.9). Remove next round.
    SequenceEmbedding_30923764532139_kernel<<<grid, block, 0, stream>>>(seq, table, out);
}

// Round 5
// 511.914 us; speedup vs baseline: 1.1643x; 1.1643x over previous
//
#include <hip/hip_runtime.h>
#include <hip/hip_bf16.h>

// FINAL — R0 structure restored (diagnostic double-launch removed).
//
// Output: (1, 8, 4096, 4096) float32, 536.9 MB written per call.
//   c in [0,4):  out[c,i,j] = table[seq[i]*4 + c]      (constant along j)
//   c in [4,8):  out[c,i,j] = table[seq[j]*4 + (c-4)]  (depends on j only)
//
// ROOFLINE EVIDENCE (R4 double-launch diagnostic): kernel's true time-share
// = 596.0 - 512.9 = 83 us for 536.9 MB of writes = 6.5 TB/s ~= 100% of the
// achievable write BW (fillBufferAligned sustains 6.2-6.35 TB/s on the same
// runs). R1-R3 alternatives (multi-store/thread, plain vs NT stores,
// persistent fill-shaped grid) were all neutral because ALL variants were
// already at the floor; the residual ~430 us of dur_us is harness overhead
// (poison-fill + dispatch gaps), not kernel time.

#define L 4096
#define TOTAL_F4 (8u * L * L / 4u)   // 33,554,432 float4 stores

typedef float v4f __attribute__((ext_vector_type(4)));
typedef int   v4i __attribute__((ext_vector_type(4)));

__global__ __launch_bounds__(256) void SequenceEmbedding_30923764532139_kernel(
        const int* __restrict__ seq,
        const float* __restrict__ table,
        v4f* __restrict__ out) {
    unsigned idx = blockIdx.x * blockDim.x + threadIdx.x;  // float4 index, exact cover
    unsigned e = idx << 2;                                  // element index (fits: 2^27)
    unsigned c = e >> 24;                                   // channel 0..7 (wave-uniform)
    unsigned i = (e >> 12) & (L - 1);                       // row (wave-uniform)
    unsigned j = e & (L - 1);                               // col, multiple of 4

    v4f val;
    if (c < 4u) {
        float x = table[(unsigned)seq[i] * 4u + c];
        val = (v4f){x, x, x, x};
    } else {
        unsigned cc = c - 4u;
        v4i s = *(const v4i*)(seq + j);                     // coalesced, 16B aligned
        val.x = table[(unsigned)s.x * 4u + cc];
        val.y = table[(unsigned)s.y * 4u + cc];
        val.z = table[(unsigned)s.z * 4u + cc];
        val.w = table[(unsigned)s.w * 4u + cc];
    }
    __builtin_nontemporal_store(val, out + idx);
}

extern "C" void kernel_launch(void* const* d_in, const int* in_sizes, int n_in,
                              void* d_out, int out_size, void* d_ws, size_t ws_size,
                              hipStream_t stream) {
    const int*   seq   = (const int*)d_in[0];
    const float* table = (const float*)d_in[1];
    v4f*         out   = (v4f*)d_out;

    dim3 block(256);
    dim3 grid(TOTAL_F4 / 256u);  // 131,072 blocks, exact cover
    SequenceEmbedding_30923764532139_kernel<<<grid, block, 0, stream>>>(seq, table, out);
}